// Round 1
// baseline (788.111 us; speedup 1.0000x reference)
//
#include <hip/hip_runtime.h>
#include <math.h>

#define N_NODES   10000
#define N_EDGES   320000
#define IN_DIM    128
#define HIDDEN    256
#define NUM_LAYERS 6
#define ALPHA     0.1f
#define LN_EPS    1e-5f

__device__ __forceinline__ float gelu_exact(float x) {
    // jax.nn.gelu(approximate=False): 0.5*x*(1+erf(x/sqrt(2)))
    return 0.5f * x * (1.0f + erff(x * 0.70710678118654752440f));
}

// ---------------- graph preprocessing ----------------

__global__ __launch_bounds__(256) void count_deg_kernel(const int* __restrict__ dst,
                                                        int* __restrict__ cnt) {
    int e = blockIdx.x * 256 + threadIdx.x;
    if (e < N_EDGES) atomicAdd(&cnt[dst[e]], 1);
}

__global__ __launch_bounds__(256) void dinv_kernel(const int* __restrict__ cnt,
                                                   float* __restrict__ dinv) {
    int i = blockIdx.x * 256 + threadIdx.x;
    // +1 for the self loop; deg >= 1 always so the deg>0 guard is moot
    if (i < N_NODES) dinv[i] = rsqrtf((float)(cnt[i] + 1));
}

// single-block exclusive scan over 10000 counts -> CSR row offsets
__global__ __launch_bounds__(256) void scan_kernel(const int* __restrict__ cnt,
                                                   int* __restrict__ offs) {
    __shared__ int sums[256];
    __shared__ int bases[257];
    int t = threadIdx.x;
    const int chunk = (N_NODES + 255) / 256;  // 40
    int b0 = t * chunk;
    int b1 = b0 + chunk; if (b1 > N_NODES) b1 = N_NODES;
    if (b0 > N_NODES) b0 = N_NODES;
    int s = 0;
    for (int i = b0; i < b1; ++i) s += cnt[i];
    sums[t] = s;
    __syncthreads();
    if (t == 0) {
        int r = 0;
        for (int i = 0; i < 256; ++i) { bases[i] = r; r += sums[i]; }
        bases[256] = r;
    }
    __syncthreads();
    int r = bases[t];
    for (int i = b0; i < b1; ++i) { offs[i] = r; r += cnt[i]; }
    if (t == 0) offs[N_NODES] = bases[256];
}

__global__ __launch_bounds__(256) void fill_csr_kernel(const int* __restrict__ src,
                                                       const int* __restrict__ dst,
                                                       const float* __restrict__ dinv,
                                                       const int* __restrict__ offs,
                                                       int* __restrict__ cursor,
                                                       int* __restrict__ csr_src,
                                                       float* __restrict__ csr_norm) {
    int e = blockIdx.x * 256 + threadIdx.x;
    if (e < N_EDGES) {
        int d = dst[e], s = src[e];
        int pos = atomicAdd(&cursor[d], 1);
        int idx = offs[d] + pos;
        csr_src[idx]  = s;
        csr_norm[idx] = dinv[s] * dinv[d];
    }
}

// ---------------- input block: Linear(128->256) + GELU + LayerNorm ----------------
// one block per node; thread c owns output column c
__global__ __launch_bounds__(256) void input_fused_kernel(const float* __restrict__ x,
                                                          const float* __restrict__ W,
                                                          const float* __restrict__ b,
                                                          const float* __restrict__ g,
                                                          const float* __restrict__ beta,
                                                          float* __restrict__ h0,
                                                          float* __restrict__ cur) {
    int n = blockIdx.x;
    int c = threadIdx.x;
    __shared__ float xs[IN_DIM];
    __shared__ float red[256];

    if (c < IN_DIM) xs[c] = x[n * IN_DIM + c];
    __syncthreads();

    float acc = b[c];
    #pragma unroll 8
    for (int k = 0; k < IN_DIM; ++k) acc += xs[k] * W[k * HIDDEN + c];

    float gv = gelu_exact(acc);

    // two-pass LayerNorm across the 256 columns of this block
    red[c] = gv; __syncthreads();
    #pragma unroll
    for (int s = 128; s > 0; s >>= 1) { if (c < s) red[c] += red[c + s]; __syncthreads(); }
    float mu = red[0] * (1.0f / 256.0f);
    __syncthreads();
    float d = gv - mu;
    red[c] = d * d; __syncthreads();
    #pragma unroll
    for (int s = 128; s > 0; s >>= 1) { if (c < s) red[c] += red[c + s]; __syncthreads(); }
    float var = red[0] * (1.0f / 256.0f);

    float val = d * rsqrtf(var + LN_EPS) * g[c] + beta[c];
    h0[n * HIDDEN + c]  = val;
    cur[n * HIDDEN + c] = val;
}

// ---------------- per-layer transform: m = cur @ Wl[l]  (fp32 tiled GEMM) ----------------
// M=10000, N=K=256.  64x64 tile, BK=16, 4x4 micro-tile per thread, 256 threads.
__global__ __launch_bounds__(256) void gemm_kernel(const float* __restrict__ A,
                                                   const float* __restrict__ B,
                                                   float* __restrict__ C) {
    __shared__ float As[16][65];  // [kk][row] with +1 pad: conflict-free col writes
    __shared__ float Bs[16][64];

    int tid = threadIdx.x;
    int tx = tid & 15;         // 16 col-groups of 4
    int ty = tid >> 4;         // 16 row-groups of 4
    int row0 = blockIdx.x * 64;
    int col0 = blockIdx.y * 64;

    float acc[4][4] = {};

    for (int k0 = 0; k0 < HIDDEN; k0 += 16) {
        // A tile 64x16: thread loads 4 consecutive K elems of one row
        {
            int idx = tid * 4;
            int r  = idx >> 4;     // 0..63
            int kk = idx & 15;     // 0,4,8,12
            int row = row0 + r;
            if (row < N_NODES) {
                const float4 a4 = *(const float4*)&A[row * HIDDEN + k0 + kk];
                As[kk + 0][r] = a4.x; As[kk + 1][r] = a4.y;
                As[kk + 2][r] = a4.z; As[kk + 3][r] = a4.w;
            } else {
                As[kk + 0][r] = 0.f; As[kk + 1][r] = 0.f;
                As[kk + 2][r] = 0.f; As[kk + 3][r] = 0.f;
            }
        }
        // B tile 16x64: thread loads 4 consecutive cols of one K row
        {
            int idx = tid * 4;
            int rb = idx >> 6;     // 0..15
            int cb = idx & 63;     // multiple of 4
            const float4 b4 = *(const float4*)&B[(k0 + rb) * HIDDEN + col0 + cb];
            *(float4*)&Bs[rb][cb] = b4;
        }
        __syncthreads();

        #pragma unroll
        for (int kk = 0; kk < 16; ++kk) {
            float a0 = As[kk][ty * 4 + 0], a1 = As[kk][ty * 4 + 1];
            float a2 = As[kk][ty * 4 + 2], a3 = As[kk][ty * 4 + 3];
            float b0 = Bs[kk][tx * 4 + 0], b1 = Bs[kk][tx * 4 + 1];
            float b2 = Bs[kk][tx * 4 + 2], b3 = Bs[kk][tx * 4 + 3];
            acc[0][0] += a0 * b0; acc[0][1] += a0 * b1; acc[0][2] += a0 * b2; acc[0][3] += a0 * b3;
            acc[1][0] += a1 * b0; acc[1][1] += a1 * b1; acc[1][2] += a1 * b2; acc[1][3] += a1 * b3;
            acc[2][0] += a2 * b0; acc[2][1] += a2 * b1; acc[2][2] += a2 * b2; acc[2][3] += a2 * b3;
            acc[3][0] += a3 * b0; acc[3][1] += a3 * b1; acc[3][2] += a3 * b2; acc[3][3] += a3 * b3;
        }
        __syncthreads();
    }

    #pragma unroll
    for (int i = 0; i < 4; ++i) {
        int row = row0 + ty * 4 + i;
        if (row < N_NODES) {
            float4 v = make_float4(acc[i][0], acc[i][1], acc[i][2], acc[i][3]);
            *(float4*)&C[row * HIDDEN + col0 + tx * 4] = v;
        }
    }
}

// ---------------- aggregation + bias + GELU + LN + residual (in-place on cur) ----------------
// one block per node; thread c owns column c.
__global__ __launch_bounds__(256) void agg_fused_kernel(const float* __restrict__ m,
                                                        const float* __restrict__ dinv,
                                                        const int* __restrict__ offs,
                                                        const int* __restrict__ csr_src,
                                                        const float* __restrict__ csr_norm,
                                                        const float* __restrict__ bias,
                                                        const float* __restrict__ g,
                                                        const float* __restrict__ beta,
                                                        const float* __restrict__ h0,
                                                        float* __restrict__ cur) {
    int n = blockIdx.x;
    int c = threadIdx.x;
    __shared__ float red[256];

    float dn = dinv[n];
    float acc = m[n * HIDDEN + c] * (dn * dn);  // self loop, norm = 1/deg

    int e0 = offs[n], e1 = offs[n + 1];
    for (int e = e0; e < e1; ++e) {
        int s   = csr_src[e];
        float w = csr_norm[e];
        acc += w * m[s * HIDDEN + c];
    }
    acc += bias[c];

    float gv = gelu_exact(acc);

    red[c] = gv; __syncthreads();
    #pragma unroll
    for (int s = 128; s > 0; s >>= 1) { if (c < s) red[c] += red[c + s]; __syncthreads(); }
    float mu = red[0] * (1.0f / 256.0f);
    __syncthreads();
    float d = gv - mu;
    red[c] = d * d; __syncthreads();
    #pragma unroll
    for (int s = 128; s > 0; s >>= 1) { if (c < s) red[c] += red[c + s]; __syncthreads(); }
    float var = red[0] * (1.0f / 256.0f);

    float hh = d * rsqrtf(var + LN_EPS) * g[c] + beta[c];

    int idx = n * HIDDEN + c;
    cur[idx] = cur[idx] + (1.0f - ALPHA) * hh + ALPHA * h0[idx];
}

// ---------------- launcher ----------------

extern "C" void kernel_launch(void* const* d_in, const int* in_sizes, int n_in,
                              void* d_out, int out_size, void* d_ws, size_t ws_size,
                              hipStream_t stream) {
    const float* x      = (const float*)d_in[0];
    const int*   ei     = (const int*)  d_in[1];   // (2, E): [0]=src row, [1]=dst row
    const float* W_in   = (const float*)d_in[2];
    const float* b_in   = (const float*)d_in[3];
    const float* g_in   = (const float*)d_in[4];
    const float* bt_in  = (const float*)d_in[5];
    const float* Wl     = (const float*)d_in[6];   // (L, 256, 256)
    const float* bl     = (const float*)d_in[7];   // (L, 256)
    const float* gl     = (const float*)d_in[8];
    const float* betal  = (const float*)d_in[9];

    const int* src = ei;
    const int* dst = ei + N_EDGES;

    float* cur = (float*)d_out;   // cur lives in d_out; final layer output lands here

    // workspace carve-up (re-poisoned to 0xAA every call -> re-init everything)
    char* w = (char*)d_ws;
    size_t off = 0;
    auto alloc = [&](size_t bytes) -> void* {
        void* p = w + off;
        off = (off + bytes + 255) & ~(size_t)255;
        return p;
    };
    int*   cnt      = (int*)  alloc(N_NODES * sizeof(int));
    int*   cursor   = (int*)  alloc(N_NODES * sizeof(int));
    int*   offs     = (int*)  alloc((N_NODES + 1) * sizeof(int));
    float* dinv     = (float*)alloc(N_NODES * sizeof(float));
    int*   csr_src  = (int*)  alloc(N_EDGES * sizeof(int));
    float* csr_norm = (float*)alloc(N_EDGES * sizeof(float));
    float* h0       = (float*)alloc((size_t)N_NODES * HIDDEN * sizeof(float));
    float* m        = (float*)alloc((size_t)N_NODES * HIDDEN * sizeof(float));

    hipMemsetAsync(cnt,    0, N_NODES * sizeof(int), stream);
    hipMemsetAsync(cursor, 0, N_NODES * sizeof(int), stream);

    const int EB = (N_EDGES + 255) / 256;
    const int NB = (N_NODES + 255) / 256;

    count_deg_kernel<<<EB, 256, 0, stream>>>(dst, cnt);
    dinv_kernel<<<NB, 256, 0, stream>>>(cnt, dinv);
    scan_kernel<<<1, 256, 0, stream>>>(cnt, offs);
    fill_csr_kernel<<<EB, 256, 0, stream>>>(src, dst, dinv, offs, cursor, csr_src, csr_norm);

    input_fused_kernel<<<N_NODES, 256, 0, stream>>>(x, W_in, b_in, g_in, bt_in, h0, cur);

    dim3 ggrid((N_NODES + 63) / 64, HIDDEN / 64);
    for (int l = 0; l < NUM_LAYERS; ++l) {
        gemm_kernel<<<ggrid, 256, 0, stream>>>(cur, Wl + (size_t)l * HIDDEN * HIDDEN, m);
        agg_fused_kernel<<<N_NODES, 256, 0, stream>>>(m, dinv, offs, csr_src, csr_norm,
                                                      bl + l * HIDDEN, gl + l * HIDDEN,
                                                      betal + l * HIDDEN, h0, cur);
    }
}

// Round 3
// 559.420 us; speedup vs baseline: 1.4088x; 1.4088x over previous
//
#include <hip/hip_runtime.h>
#include <math.h>

#define N_NODES   10000
#define N_EDGES   320000
#define IN_DIM    128
#define HIDDEN    256
#define NUM_LAYERS 6
#define ALPHA     0.1f
#define LN_EPS    1e-5f

__device__ __forceinline__ float gelu_exact(float x) {
    // jax.nn.gelu(approximate=False): 0.5*x*(1+erf(x/sqrt(2)))
    return 0.5f * x * (1.0f + erff(x * 0.70710678118654752440f));
}

__device__ __forceinline__ float wave_sum64(float v) {
#pragma unroll
    for (int i = 32; i > 0; i >>= 1) v += __shfl_xor(v, i);
    return v;
}

// ---------------- graph preprocessing ----------------

__global__ __launch_bounds__(256) void count_deg_kernel(const int* __restrict__ dst,
                                                        int* __restrict__ cnt) {
    int e = blockIdx.x * 256 + threadIdx.x;
    if (e < N_EDGES) atomicAdd(&cnt[dst[e]], 1);
}

__global__ __launch_bounds__(256) void dinv_kernel(const int* __restrict__ cnt,
                                                   float* __restrict__ dinv) {
    int i = blockIdx.x * 256 + threadIdx.x;
    // +1 for the self loop; deg >= 1 always so the deg>0 guard is moot
    if (i < N_NODES) dinv[i] = rsqrtf((float)(cnt[i] + 1));
}

// single-block exclusive scan over 10000 counts -> CSR row offsets
__global__ __launch_bounds__(256) void scan_kernel(const int* __restrict__ cnt,
                                                   int* __restrict__ offs) {
    __shared__ int sums[256];
    __shared__ int bases[257];
    int t = threadIdx.x;
    const int chunk = (N_NODES + 255) / 256;  // 40
    int b0 = t * chunk;
    int b1 = b0 + chunk; if (b1 > N_NODES) b1 = N_NODES;
    if (b0 > N_NODES) b0 = N_NODES;
    int s = 0;
    for (int i = b0; i < b1; ++i) s += cnt[i];
    sums[t] = s;
    __syncthreads();
    if (t == 0) {
        int r = 0;
        for (int i = 0; i < 256; ++i) { bases[i] = r; r += sums[i]; }
        bases[256] = r;
    }
    __syncthreads();
    int r = bases[t];
    for (int i = b0; i < b1; ++i) { offs[i] = r; r += cnt[i]; }
    if (t == 0) offs[N_NODES] = bases[256];
}

__global__ __launch_bounds__(256) void fill_csr_kernel(const int* __restrict__ src,
                                                       const int* __restrict__ dst,
                                                       const float* __restrict__ dinv,
                                                       const int* __restrict__ offs,
                                                       int* __restrict__ cursor,
                                                       int* __restrict__ csr_src,
                                                       float* __restrict__ csr_norm) {
    int e = blockIdx.x * 256 + threadIdx.x;
    if (e < N_EDGES) {
        int d = dst[e], s = src[e];
        int pos = atomicAdd(&cursor[d], 1);
        int idx = offs[d] + pos;
        csr_src[idx]  = s;
        csr_norm[idx] = dinv[s] * dinv[d];
    }
}

// ---------------- tiled fp32 GEMM: C[M,256] = A[M,K] @ B[K,256] ----------------
// 64x64 tile, BK=16, 4x4 micro-tile per thread, 256 threads.
template<int K>
__global__ __launch_bounds__(256) void gemm_kernel(const float* __restrict__ A,
                                                   const float* __restrict__ B,
                                                   float* __restrict__ C) {
    __shared__ float As[16][65];  // [kk][row] with +1 pad
    __shared__ float Bs[16][64];

    int tid = threadIdx.x;
    int tx = tid & 15;
    int ty = tid >> 4;
    int row0 = blockIdx.x * 64;
    int col0 = blockIdx.y * 64;

    float acc[4][4] = {};

    for (int k0 = 0; k0 < K; k0 += 16) {
        {
            int idx = tid * 4;
            int r  = idx >> 4;     // 0..63
            int kk = idx & 15;     // 0,4,8,12
            int row = row0 + r;
            if (row < N_NODES) {
                const float4 a4 = *(const float4*)&A[(size_t)row * K + k0 + kk];
                As[kk + 0][r] = a4.x; As[kk + 1][r] = a4.y;
                As[kk + 2][r] = a4.z; As[kk + 3][r] = a4.w;
            } else {
                As[kk + 0][r] = 0.f; As[kk + 1][r] = 0.f;
                As[kk + 2][r] = 0.f; As[kk + 3][r] = 0.f;
            }
        }
        {
            int idx = tid * 4;
            int rb = idx >> 6;     // 0..15
            int cb = idx & 63;     // multiple of 4
            const float4 b4 = *(const float4*)&B[(size_t)(k0 + rb) * HIDDEN + col0 + cb];
            *(float4*)&Bs[rb][cb] = b4;
        }
        __syncthreads();

        #pragma unroll
        for (int kk = 0; kk < 16; ++kk) {
            float a0 = As[kk][ty * 4 + 0], a1 = As[kk][ty * 4 + 1];
            float a2 = As[kk][ty * 4 + 2], a3 = As[kk][ty * 4 + 3];
            float b0 = Bs[kk][tx * 4 + 0], b1 = Bs[kk][tx * 4 + 1];
            float b2 = Bs[kk][tx * 4 + 2], b3 = Bs[kk][tx * 4 + 3];
            acc[0][0] += a0 * b0; acc[0][1] += a0 * b1; acc[0][2] += a0 * b2; acc[0][3] += a0 * b3;
            acc[1][0] += a1 * b0; acc[1][1] += a1 * b1; acc[1][2] += a1 * b2; acc[1][3] += a1 * b3;
            acc[2][0] += a2 * b0; acc[2][1] += a2 * b1; acc[2][2] += a2 * b2; acc[2][3] += a2 * b3;
            acc[3][0] += a3 * b0; acc[3][1] += a3 * b1; acc[3][2] += a3 * b2; acc[3][3] += a3 * b3;
        }
        __syncthreads();
    }

    #pragma unroll
    for (int i = 0; i < 4; ++i) {
        int row = row0 + ty * 4 + i;
        if (row < N_NODES) {
            float4 v = make_float4(acc[i][0], acc[i][1], acc[i][2], acc[i][3]);
            *(float4*)&C[(size_t)row * HIDDEN + col0 + tx * 4] = v;
        }
    }
}

// ---------------- input epilogue: GELU + LN on pre-activation, write h0 and cur ----------------
// one WAVE per node, 4 nodes per block; lane owns 4 columns (float4); LN via shuffles.
__global__ __launch_bounds__(256) void ln_in_kernel(const float4* __restrict__ pre,
                                                    const float4* __restrict__ b4,
                                                    const float4* __restrict__ g4,
                                                    const float4* __restrict__ beta4,
                                                    float4* __restrict__ h0,
                                                    float4* __restrict__ cur) {
    int n = blockIdx.x * 4 + (threadIdx.x >> 6);
    int lane = threadIdx.x & 63;
    if (n >= N_NODES) return;

    float4 v = pre[(size_t)n * 64 + lane];
    float4 bb = b4[lane];
    float x0 = gelu_exact(v.x + bb.x);
    float x1 = gelu_exact(v.y + bb.y);
    float x2 = gelu_exact(v.z + bb.z);
    float x3 = gelu_exact(v.w + bb.w);

    float mu = wave_sum64(x0 + x1 + x2 + x3) * (1.0f / 256.0f);
    float d0 = x0 - mu, d1 = x1 - mu, d2 = x2 - mu, d3 = x3 - mu;
    float var = wave_sum64(d0 * d0 + d1 * d1 + d2 * d2 + d3 * d3) * (1.0f / 256.0f);
    float r = rsqrtf(var + LN_EPS);

    float4 gg = g4[lane], be = beta4[lane];
    float4 out = make_float4(d0 * r * gg.x + be.x, d1 * r * gg.y + be.y,
                             d2 * r * gg.z + be.z, d3 * r * gg.w + be.w);
    h0[(size_t)n * 64 + lane]  = out;
    cur[(size_t)n * 64 + lane] = out;
}

// ---------------- aggregation + bias + GELU + LN + residual (in-place on cur) ----------------
// one WAVE per node (4 nodes/block); lane owns 4 columns via float4; edge loop unrolled x4
// for memory-level parallelism; LN via wave shuffles (no LDS, no barriers).
__global__ __launch_bounds__(256) void agg_fused_kernel(const float4* __restrict__ m4,
                                                        const float* __restrict__ dinv,
                                                        const int* __restrict__ offs,
                                                        const int* __restrict__ csr_src,
                                                        const float* __restrict__ csr_norm,
                                                        const float4* __restrict__ bias4,
                                                        const float4* __restrict__ g4,
                                                        const float4* __restrict__ beta4,
                                                        const float4* __restrict__ h04,
                                                        float4* __restrict__ cur4) {
    int n = blockIdx.x * 4 + (threadIdx.x >> 6);
    int lane = threadIdx.x & 63;
    if (n >= N_NODES) return;

    float dn = dinv[n];
    float dn2 = dn * dn;
    float4 sv = m4[(size_t)n * 64 + lane];          // self loop
    float ax = sv.x * dn2, ay = sv.y * dn2, az = sv.z * dn2, aw = sv.w * dn2;

    int e  = offs[n];
    int e1 = offs[n + 1];
    for (; e + 3 < e1; e += 4) {
        int s0 = csr_src[e + 0], s1 = csr_src[e + 1];
        int s2 = csr_src[e + 2], s3 = csr_src[e + 3];
        float w0 = csr_norm[e + 0], w1 = csr_norm[e + 1];
        float w2 = csr_norm[e + 2], w3 = csr_norm[e + 3];
        float4 v0 = m4[(size_t)s0 * 64 + lane];
        float4 v1 = m4[(size_t)s1 * 64 + lane];
        float4 v2 = m4[(size_t)s2 * 64 + lane];
        float4 v3 = m4[(size_t)s3 * 64 + lane];
        ax += w0 * v0.x + w1 * v1.x + w2 * v2.x + w3 * v3.x;
        ay += w0 * v0.y + w1 * v1.y + w2 * v2.y + w3 * v3.y;
        az += w0 * v0.z + w1 * v1.z + w2 * v2.z + w3 * v3.z;
        aw += w0 * v0.w + w1 * v1.w + w2 * v2.w + w3 * v3.w;
    }
    for (; e < e1; ++e) {
        int s = csr_src[e];
        float w = csr_norm[e];
        float4 vv = m4[(size_t)s * 64 + lane];
        ax += w * vv.x; ay += w * vv.y; az += w * vv.z; aw += w * vv.w;
    }

    float4 bb = bias4[lane];
    float x0 = gelu_exact(ax + bb.x);
    float x1 = gelu_exact(ay + bb.y);
    float x2 = gelu_exact(az + bb.z);
    float x3 = gelu_exact(aw + bb.w);

    float mu = wave_sum64(x0 + x1 + x2 + x3) * (1.0f / 256.0f);
    float d0 = x0 - mu, d1 = x1 - mu, d2 = x2 - mu, d3 = x3 - mu;
    float var = wave_sum64(d0 * d0 + d1 * d1 + d2 * d2 + d3 * d3) * (1.0f / 256.0f);
    float r = rsqrtf(var + LN_EPS);

    float4 gg = g4[lane], be = beta4[lane];
    float h0v = d0 * r * gg.x + be.x;
    float h1v = d1 * r * gg.y + be.y;
    float h2v = d2 * r * gg.z + be.z;
    float h3v = d3 * r * gg.w + be.w;

    size_t idx = (size_t)n * 64 + lane;
    float4 c = cur4[idx];
    float4 h = h04[idx];
    float4 o = make_float4(c.x + (1.0f - ALPHA) * h0v + ALPHA * h.x,
                           c.y + (1.0f - ALPHA) * h1v + ALPHA * h.y,
                           c.z + (1.0f - ALPHA) * h2v + ALPHA * h.z,
                           c.w + (1.0f - ALPHA) * h3v + ALPHA * h.w);
    cur4[idx] = o;
}

// ---------------- launcher ----------------

extern "C" void kernel_launch(void* const* d_in, const int* in_sizes, int n_in,
                              void* d_out, int out_size, void* d_ws, size_t ws_size,
                              hipStream_t stream) {
    const float* x      = (const float*)d_in[0];
    const int*   ei     = (const int*)  d_in[1];   // (2, E): [0]=src, [1]=dst
    const float* W_in   = (const float*)d_in[2];
    const float* b_in   = (const float*)d_in[3];
    const float* g_in   = (const float*)d_in[4];
    const float* bt_in  = (const float*)d_in[5];
    const float* Wl     = (const float*)d_in[6];   // (L, 256, 256)
    const float* bl     = (const float*)d_in[7];
    const float* gl     = (const float*)d_in[8];
    const float* betal  = (const float*)d_in[9];

    const int* src = ei;
    const int* dst = ei + N_EDGES;

    float* cur = (float*)d_out;

    char* w = (char*)d_ws;
    size_t off = 0;
    auto alloc = [&](size_t bytes) -> void* {
        void* p = w + off;
        off = (off + bytes + 255) & ~(size_t)255;
        return p;
    };
    int*   cnt      = (int*)  alloc(N_NODES * sizeof(int));
    int*   cursor   = (int*)  alloc(N_NODES * sizeof(int));
    int*   offs     = (int*)  alloc((N_NODES + 1) * sizeof(int));
    float* dinv     = (float*)alloc(N_NODES * sizeof(float));
    int*   csr_src  = (int*)  alloc(N_EDGES * sizeof(int));
    float* csr_norm = (float*)alloc(N_EDGES * sizeof(float));
    float* h0       = (float*)alloc((size_t)N_NODES * HIDDEN * sizeof(float));
    float* m        = (float*)alloc((size_t)N_NODES * HIDDEN * sizeof(float));

    hipMemsetAsync(cnt,    0, N_NODES * sizeof(int), stream);
    hipMemsetAsync(cursor, 0, N_NODES * sizeof(int), stream);

    const int EB = (N_EDGES + 255) / 256;
    const int NB = (N_NODES + 255) / 256;
    const int NODE_BLOCKS = (N_NODES + 3) / 4;   // 1 wave per node, 4 nodes/block

    count_deg_kernel<<<EB, 256, 0, stream>>>(dst, cnt);
    dinv_kernel<<<NB, 256, 0, stream>>>(cnt, dinv);
    scan_kernel<<<1, 256, 0, stream>>>(cnt, offs);
    fill_csr_kernel<<<EB, 256, 0, stream>>>(src, dst, dinv, offs, cursor, csr_src, csr_norm);

    dim3 ggrid((N_NODES + 63) / 64, HIDDEN / 64);

    // input block: GEMM (K=128) -> fused GELU+LN writing h0 and cur
    gemm_kernel<IN_DIM><<<ggrid, 256, 0, stream>>>(x, W_in, m);
    ln_in_kernel<<<NODE_BLOCKS, 256, 0, stream>>>((const float4*)m, (const float4*)b_in,
                                                  (const float4*)g_in, (const float4*)bt_in,
                                                  (float4*)h0, (float4*)cur);

    for (int l = 0; l < NUM_LAYERS; ++l) {
        gemm_kernel<HIDDEN><<<ggrid, 256, 0, stream>>>(cur, Wl + (size_t)l * HIDDEN * HIDDEN, m);
        agg_fused_kernel<<<NODE_BLOCKS, 256, 0, stream>>>((const float4*)m, dinv, offs,
                                                          csr_src, csr_norm,
                                                          (const float4*)(bl + l * HIDDEN),
                                                          (const float4*)(gl + l * HIDDEN),
                                                          (const float4*)(betal + l * HIDDEN),
                                                          (const float4*)h0, (float4*)cur);
    }
}

// Round 4
// 558.613 us; speedup vs baseline: 1.4108x; 1.0014x over previous
//
#include <hip/hip_runtime.h>
#include <math.h>

#define N_NODES   10000
#define N_EDGES   320000
#define IN_DIM    128
#define HIDDEN    256
#define NUM_LAYERS 6
#define ALPHA     0.1f
#define LN_EPS    1e-5f

__device__ __forceinline__ float gelu_exact(float x) {
    // jax.nn.gelu(approximate=False): 0.5*x*(1+erf(x/sqrt(2)))
    return 0.5f * x * (1.0f + erff(x * 0.70710678118654752440f));
}

__device__ __forceinline__ float wave_sum64(float v) {
#pragma unroll
    for (int i = 32; i > 0; i >>= 1) v += __shfl_xor(v, i);
    return v;
}

// ---------------- graph preprocessing ----------------

__global__ __launch_bounds__(256) void count_deg_kernel(const int* __restrict__ dst,
                                                        int* __restrict__ cnt) {
    int e = blockIdx.x * 256 + threadIdx.x;
    if (e < N_EDGES) atomicAdd(&cnt[dst[e]], 1);
}

__global__ __launch_bounds__(256) void dinv_kernel(const int* __restrict__ cnt,
                                                   float* __restrict__ dinv) {
    int i = blockIdx.x * 256 + threadIdx.x;
    // +1 for the self loop; deg >= 1 always so the deg>0 guard is moot
    if (i < N_NODES) dinv[i] = rsqrtf((float)(cnt[i] + 1));
}

// single-block exclusive scan over 10000 counts -> CSR row offsets
__global__ __launch_bounds__(256) void scan_kernel(const int* __restrict__ cnt,
                                                   int* __restrict__ offs) {
    __shared__ int sums[256];
    __shared__ int bases[257];
    int t = threadIdx.x;
    const int chunk = (N_NODES + 255) / 256;  // 40
    int b0 = t * chunk;
    int b1 = b0 + chunk; if (b1 > N_NODES) b1 = N_NODES;
    if (b0 > N_NODES) b0 = N_NODES;
    int s = 0;
    for (int i = b0; i < b1; ++i) s += cnt[i];
    sums[t] = s;
    __syncthreads();
    if (t == 0) {
        int r = 0;
        for (int i = 0; i < 256; ++i) { bases[i] = r; r += sums[i]; }
        bases[256] = r;
    }
    __syncthreads();
    int r = bases[t];
    for (int i = b0; i < b1; ++i) { offs[i] = r; r += cnt[i]; }
    if (t == 0) offs[N_NODES] = bases[256];
}

__global__ __launch_bounds__(256) void fill_csr_kernel(const int* __restrict__ src,
                                                       const int* __restrict__ dst,
                                                       const float* __restrict__ dinv,
                                                       const int* __restrict__ offs,
                                                       int* __restrict__ cursor,
                                                       int* __restrict__ csr_src,
                                                       float* __restrict__ csr_norm) {
    int e = blockIdx.x * 256 + threadIdx.x;
    if (e < N_EDGES) {
        int d = dst[e], s = src[e];
        int pos = atomicAdd(&cursor[d], 1);
        int idx = offs[d] + pos;
        csr_src[idx]  = s;
        csr_norm[idx] = dinv[s] * dinv[d];
    }
}

// ---------------- tiled fp32 GEMM: C[M,256] = A[M,K] @ B[K,256] ----------------
// 64x64 tile, BK=16, 4x4 micro-tile per thread, 256 threads.
// LDS rows padded to 68 floats (272 B = 17*16) so fragment reads are 16B-aligned
// float4 (ds_read_b128, ~2x the byte throughput of scalar ds_read_b32).
template<int K>
__global__ __launch_bounds__(256) void gemm_kernel(const float* __restrict__ A,
                                                   const float* __restrict__ B,
                                                   float* __restrict__ C) {
    __shared__ float As[16][68];  // [kk][row], stride 272 B (16B-aligned, 4-bank skew/row)
    __shared__ float Bs[16][68];  // [kk][col]

    int tid = threadIdx.x;
    int tx = tid & 15;
    int ty = tid >> 4;
    int row0 = blockIdx.x * 64;
    int col0 = blockIdx.y * 64;

    float acc[4][4] = {};

    for (int k0 = 0; k0 < K; k0 += 16) {
        {
            int idx = tid * 4;
            int r  = idx >> 4;     // 0..63
            int kk = idx & 15;     // 0,4,8,12
            int row = row0 + r;
            if (row < N_NODES) {
                const float4 a4 = *(const float4*)&A[(size_t)row * K + k0 + kk];
                As[kk + 0][r] = a4.x; As[kk + 1][r] = a4.y;
                As[kk + 2][r] = a4.z; As[kk + 3][r] = a4.w;
            } else {
                As[kk + 0][r] = 0.f; As[kk + 1][r] = 0.f;
                As[kk + 2][r] = 0.f; As[kk + 3][r] = 0.f;
            }
        }
        {
            int idx = tid * 4;
            int rb = idx >> 6;     // 0..15
            int cb = idx & 63;     // multiple of 4
            const float4 b4 = *(const float4*)&B[(size_t)(k0 + rb) * HIDDEN + col0 + cb];
            *(float4*)&Bs[rb][cb] = b4;
        }
        __syncthreads();

        #pragma unroll
        for (int kk = 0; kk < 16; ++kk) {
            const float4 a4 = *(const float4*)&As[kk][ty * 4];
            const float4 b4 = *(const float4*)&Bs[kk][tx * 4];
            acc[0][0] += a4.x * b4.x; acc[0][1] += a4.x * b4.y; acc[0][2] += a4.x * b4.z; acc[0][3] += a4.x * b4.w;
            acc[1][0] += a4.y * b4.x; acc[1][1] += a4.y * b4.y; acc[1][2] += a4.y * b4.z; acc[1][3] += a4.y * b4.w;
            acc[2][0] += a4.z * b4.x; acc[2][1] += a4.z * b4.y; acc[2][2] += a4.z * b4.z; acc[2][3] += a4.z * b4.w;
            acc[3][0] += a4.w * b4.x; acc[3][1] += a4.w * b4.y; acc[3][2] += a4.w * b4.z; acc[3][3] += a4.w * b4.w;
        }
        __syncthreads();
    }

    #pragma unroll
    for (int i = 0; i < 4; ++i) {
        int row = row0 + ty * 4 + i;
        if (row < N_NODES) {
            float4 v = make_float4(acc[i][0], acc[i][1], acc[i][2], acc[i][3]);
            *(float4*)&C[(size_t)row * HIDDEN + col0 + tx * 4] = v;
        }
    }
}

// ---------------- input epilogue: GELU + LN on pre-activation, write h0 and cur ----------------
// one WAVE per node, 4 nodes per block; lane owns 4 columns (float4); LN via shuffles.
__global__ __launch_bounds__(256) void ln_in_kernel(const float4* __restrict__ pre,
                                                    const float4* __restrict__ b4,
                                                    const float4* __restrict__ g4,
                                                    const float4* __restrict__ beta4,
                                                    float4* __restrict__ h0,
                                                    float4* __restrict__ cur) {
    int n = blockIdx.x * 4 + (threadIdx.x >> 6);
    int lane = threadIdx.x & 63;
    if (n >= N_NODES) return;

    float4 v = pre[(size_t)n * 64 + lane];
    float4 bb = b4[lane];
    float x0 = gelu_exact(v.x + bb.x);
    float x1 = gelu_exact(v.y + bb.y);
    float x2 = gelu_exact(v.z + bb.z);
    float x3 = gelu_exact(v.w + bb.w);

    float mu = wave_sum64(x0 + x1 + x2 + x3) * (1.0f / 256.0f);
    float d0 = x0 - mu, d1 = x1 - mu, d2 = x2 - mu, d3 = x3 - mu;
    float var = wave_sum64(d0 * d0 + d1 * d1 + d2 * d2 + d3 * d3) * (1.0f / 256.0f);
    float r = rsqrtf(var + LN_EPS);

    float4 gg = g4[lane], be = beta4[lane];
    float4 out = make_float4(d0 * r * gg.x + be.x, d1 * r * gg.y + be.y,
                             d2 * r * gg.z + be.z, d3 * r * gg.w + be.w);
    h0[(size_t)n * 64 + lane]  = out;
    cur[(size_t)n * 64 + lane] = out;
}

// ---------------- aggregation + bias + GELU + LN + residual (in-place on cur) ----------------
// one WAVE per node (4 nodes/block); lane owns 4 columns via float4; edge loop unrolled x8
// (8 outstanding 1KB gathers per wave) ; LN via wave shuffles (no LDS, no barriers).
__global__ __launch_bounds__(256) void agg_fused_kernel(const float4* __restrict__ m4,
                                                        const float* __restrict__ dinv,
                                                        const int* __restrict__ offs,
                                                        const int* __restrict__ csr_src,
                                                        const float* __restrict__ csr_norm,
                                                        const float4* __restrict__ bias4,
                                                        const float4* __restrict__ g4,
                                                        const float4* __restrict__ beta4,
                                                        const float4* __restrict__ h04,
                                                        float4* __restrict__ cur4) {
    int n = blockIdx.x * 4 + (threadIdx.x >> 6);
    int lane = threadIdx.x & 63;
    if (n >= N_NODES) return;

    float dn = dinv[n];
    float dn2 = dn * dn;
    float4 sv = m4[(size_t)n * 64 + lane];          // self loop
    float ax = sv.x * dn2, ay = sv.y * dn2, az = sv.z * dn2, aw = sv.w * dn2;

    int e  = offs[n];
    int e1 = offs[n + 1];
    for (; e + 7 < e1; e += 8) {
        int   s0 = csr_src[e + 0], s1 = csr_src[e + 1], s2 = csr_src[e + 2], s3 = csr_src[e + 3];
        int   s4 = csr_src[e + 4], s5 = csr_src[e + 5], s6 = csr_src[e + 6], s7 = csr_src[e + 7];
        float w0 = csr_norm[e + 0], w1 = csr_norm[e + 1], w2 = csr_norm[e + 2], w3 = csr_norm[e + 3];
        float w4 = csr_norm[e + 4], w5 = csr_norm[e + 5], w6 = csr_norm[e + 6], w7 = csr_norm[e + 7];
        float4 v0 = m4[(size_t)s0 * 64 + lane];
        float4 v1 = m4[(size_t)s1 * 64 + lane];
        float4 v2 = m4[(size_t)s2 * 64 + lane];
        float4 v3 = m4[(size_t)s3 * 64 + lane];
        float4 v4 = m4[(size_t)s4 * 64 + lane];
        float4 v5 = m4[(size_t)s5 * 64 + lane];
        float4 v6 = m4[(size_t)s6 * 64 + lane];
        float4 v7 = m4[(size_t)s7 * 64 + lane];
        ax += w0 * v0.x + w1 * v1.x + w2 * v2.x + w3 * v3.x;
        ay += w0 * v0.y + w1 * v1.y + w2 * v2.y + w3 * v3.y;
        az += w0 * v0.z + w1 * v1.z + w2 * v2.z + w3 * v3.z;
        aw += w0 * v0.w + w1 * v1.w + w2 * v2.w + w3 * v3.w;
        ax += w4 * v4.x + w5 * v5.x + w6 * v6.x + w7 * v7.x;
        ay += w4 * v4.y + w5 * v5.y + w6 * v6.y + w7 * v7.y;
        az += w4 * v4.z + w5 * v5.z + w6 * v6.z + w7 * v7.z;
        aw += w4 * v4.w + w5 * v5.w + w6 * v6.w + w7 * v7.w;
    }
    for (; e < e1; ++e) {
        int s = csr_src[e];
        float w = csr_norm[e];
        float4 vv = m4[(size_t)s * 64 + lane];
        ax += w * vv.x; ay += w * vv.y; az += w * vv.z; aw += w * vv.w;
    }

    float4 bb = bias4[lane];
    float x0 = gelu_exact(ax + bb.x);
    float x1 = gelu_exact(ay + bb.y);
    float x2 = gelu_exact(az + bb.z);
    float x3 = gelu_exact(aw + bb.w);

    float mu = wave_sum64(x0 + x1 + x2 + x3) * (1.0f / 256.0f);
    float d0 = x0 - mu, d1 = x1 - mu, d2 = x2 - mu, d3 = x3 - mu;
    float var = wave_sum64(d0 * d0 + d1 * d1 + d2 * d2 + d3 * d3) * (1.0f / 256.0f);
    float r = rsqrtf(var + LN_EPS);

    float4 gg = g4[lane], be = beta4[lane];
    float h0v = d0 * r * gg.x + be.x;
    float h1v = d1 * r * gg.y + be.y;
    float h2v = d2 * r * gg.z + be.z;
    float h3v = d3 * r * gg.w + be.w;

    size_t idx = (size_t)n * 64 + lane;
    float4 c = cur4[idx];
    float4 h = h04[idx];
    float4 o = make_float4(c.x + (1.0f - ALPHA) * h0v + ALPHA * h.x,
                           c.y + (1.0f - ALPHA) * h1v + ALPHA * h.y,
                           c.z + (1.0f - ALPHA) * h2v + ALPHA * h.z,
                           c.w + (1.0f - ALPHA) * h3v + ALPHA * h.w);
    cur4[idx] = o;
}

// ---------------- launcher ----------------

extern "C" void kernel_launch(void* const* d_in, const int* in_sizes, int n_in,
                              void* d_out, int out_size, void* d_ws, size_t ws_size,
                              hipStream_t stream) {
    const float* x      = (const float*)d_in[0];
    const int*   ei     = (const int*)  d_in[1];   // (2, E): [0]=src, [1]=dst
    const float* W_in   = (const float*)d_in[2];
    const float* b_in   = (const float*)d_in[3];
    const float* g_in   = (const float*)d_in[4];
    const float* bt_in  = (const float*)d_in[5];
    const float* Wl     = (const float*)d_in[6];   // (L, 256, 256)
    const float* bl     = (const float*)d_in[7];
    const float* gl     = (const float*)d_in[8];
    const float* betal  = (const float*)d_in[9];

    const int* src = ei;
    const int* dst = ei + N_EDGES;

    float* cur = (float*)d_out;

    char* w = (char*)d_ws;
    size_t off = 0;
    auto alloc = [&](size_t bytes) -> void* {
        void* p = w + off;
        off = (off + bytes + 255) & ~(size_t)255;
        return p;
    };
    int*   cnt      = (int*)  alloc(N_NODES * sizeof(int));
    int*   cursor   = (int*)  alloc(N_NODES * sizeof(int));
    int*   offs     = (int*)  alloc((N_NODES + 1) * sizeof(int));
    float* dinv     = (float*)alloc(N_NODES * sizeof(float));
    int*   csr_src  = (int*)  alloc(N_EDGES * sizeof(int));
    float* csr_norm = (float*)alloc(N_EDGES * sizeof(float));
    float* h0       = (float*)alloc((size_t)N_NODES * HIDDEN * sizeof(float));
    float* m        = (float*)alloc((size_t)N_NODES * HIDDEN * sizeof(float));

    hipMemsetAsync(cnt,    0, N_NODES * sizeof(int), stream);
    hipMemsetAsync(cursor, 0, N_NODES * sizeof(int), stream);

    const int EB = (N_EDGES + 255) / 256;
    const int NB = (N_NODES + 255) / 256;
    const int NODE_BLOCKS = (N_NODES + 3) / 4;   // 1 wave per node, 4 nodes/block

    count_deg_kernel<<<EB, 256, 0, stream>>>(dst, cnt);
    dinv_kernel<<<NB, 256, 0, stream>>>(cnt, dinv);
    scan_kernel<<<1, 256, 0, stream>>>(cnt, offs);
    fill_csr_kernel<<<EB, 256, 0, stream>>>(src, dst, dinv, offs, cursor, csr_src, csr_norm);

    dim3 ggrid((N_NODES + 63) / 64, HIDDEN / 64);

    // input block: GEMM (K=128) -> fused GELU+LN writing h0 and cur
    gemm_kernel<IN_DIM><<<ggrid, 256, 0, stream>>>(x, W_in, m);
    ln_in_kernel<<<NODE_BLOCKS, 256, 0, stream>>>((const float4*)m, (const float4*)b_in,
                                                  (const float4*)g_in, (const float4*)bt_in,
                                                  (float4*)h0, (float4*)cur);

    for (int l = 0; l < NUM_LAYERS; ++l) {
        gemm_kernel<HIDDEN><<<ggrid, 256, 0, stream>>>(cur, Wl + (size_t)l * HIDDEN * HIDDEN, m);
        agg_fused_kernel<<<NODE_BLOCKS, 256, 0, stream>>>((const float4*)m, dinv, offs,
                                                          csr_src, csr_norm,
                                                          (const float4*)(bl + l * HIDDEN),
                                                          (const float4*)(gl + l * HIDDEN),
                                                          (const float4*)(betal + l * HIDDEN),
                                                          (const float4*)h0, (float4*)cur);
    }
}